// Round 1
// baseline (1318.576 us; speedup 1.0000x reference)
//
#include <hip/hip_runtime.h>
#include <hip/hip_bf16.h>

#define H_  1024
#define B_  32
#define S_  2048
#define K2_ 2048   // 2*H

typedef __attribute__((ext_vector_type(8))) short short8;
typedef __attribute__((ext_vector_type(4))) float floatx4;
typedef __attribute__((ext_vector_type(8))) unsigned short ushortx8;

__device__ __forceinline__ unsigned short f2bf(float x) {
    unsigned int u = __float_as_uint(x);
    u += 0x7fffu + ((u >> 16) & 1u);   // round-to-nearest-even
    return (unsigned short)(u >> 16);
}

__device__ __forceinline__ float fast_tanh(float x) {
    float e = __expf(2.0f * x);
    return 1.0f - 2.0f / (e + 1.0f);
}

__device__ __forceinline__ void gload_lds16(const void* g, void* l) {
    __builtin_amdgcn_global_load_lds(
        (const __attribute__((address_space(1))) unsigned int*)g,
        (__attribute__((address_space(3))) unsigned int*)l, 16, 0, 0);
}

// ---------------- fp32 -> bf16 bulk convert ----------------
__global__ __launch_bounds__(256)
void cvt_bf16_k(const float* __restrict__ in, unsigned short* __restrict__ out, long long n8)
{
    long long i = (long long)blockIdx.x * 256 + threadIdx.x;
    long long stride = (long long)gridDim.x * 256;
    for (; i < n8; i += stride) {
        const float4* p = (const float4*)in + i * 2;
        float4 a = p[0], b = p[1];
        ushortx8 o = { f2bf(a.x), f2bf(a.y), f2bf(a.z), f2bf(a.w),
                       f2bf(b.x), f2bf(b.y), f2bf(b.z), f2bf(b.w) };
        *(ushortx8*)(out + i * 8) = o;
    }
}

// ---------------- wq[b][n] = W_b[n] + U_b[n] + sum_h dh[b][h] * W_w[n][h] ----------------
__global__ __launch_bounds__(256)
void wq_k(const float* __restrict__ dh, const float* __restrict__ Ww,
          const float* __restrict__ Wb, const float* __restrict__ Ub,
          float* __restrict__ wqbuf)
{
    const int b = blockIdx.y;
    const int n = blockIdx.x * 256 + threadIdx.x;
    const int tid = threadIdx.x;
    __shared__ float dhs[H_];
    for (int h = tid; h < H_; h += 256) dhs[h] = dh[b * H_ + h];
    __syncthreads();
    const float4* row = (const float4*)(Ww + (size_t)n * H_);
    float acc = 0.f;
    #pragma unroll 4
    for (int h4 = 0; h4 < H_ / 4; h4++) {
        float4 wv = row[h4];
        acc += wv.x * dhs[h4 * 4 + 0] + wv.y * dhs[h4 * 4 + 1]
             + wv.z * dhs[h4 * 4 + 2] + wv.w * dhs[h4 * 4 + 3];
    }
    wqbuf[b * H_ + n] = acc + Wb[n] + Ub[n];
}

// ---------------- fast path: bf16 GEMM, dbuf-prefetch + XOR-swizzled LDS ----------------
// C[m][n] = sum_k encb[b][m][k] * Uwb[n][k]; epilogue: V-dot of tanh(C + wq)
// K-step=32, double-buffered LDS; next tile's global_load_lds stay in flight across
// raw s_barrier with counted s_waitcnt vmcnt(4) (never 0 in the main loop).
// Bank conflicts: row-major [128][32] (64B rows) had lanes 0..15 on one 16B column
// -> XOR the 16B k-chunk with (row&3). Swizzle is applied to the GLOBAL source
// address (lane-permute within each quad: same 64B line, coalescing preserved,
// LDS dest stays linear per the global_load_lds scatter rule) and to the ds_read slot.
__global__ __launch_bounds__(256)
void gemm_scores_bf16(const unsigned short* __restrict__ encb,
                      const unsigned short* __restrict__ Uwb,
                      const float* __restrict__ wqbuf, const float* __restrict__ Vw,
                      float* __restrict__ partial)
{
    const int b   = blockIdx.z;
    const int mt  = blockIdx.x;   // 16 tiles of 128 rows (s)
    const int nt  = blockIdx.y;   // 8 tiles of 128 cols (hidden)
    const int tid = threadIdx.x;
    const int wave = tid >> 6;
    const int lane = tid & 63;

    __shared__ unsigned short As[2][128 * 32];
    __shared__ unsigned short Bs[2][128 * 32];
    __shared__ float sc[2][128];

    const unsigned short* Ag = encb + ((size_t)b * S_ + (size_t)mt * 128) * K2_;
    const unsigned short* Bg = Uwb + (size_t)nt * 128 * K2_;

    floatx4 acc[4][4];
    #pragma unroll
    for (int i = 0; i < 4; i++)
        #pragma unroll
        for (int j = 0; j < 4; j++)
            acc[i][j] = (floatx4){0.f, 0.f, 0.f, 0.f};

    const int wm  = (wave & 1) * 64;
    const int wn  = (wave >> 1) * 64;
    const int l15 = lane & 15;

    // ---- staging addressing (wave w covers rows [w*32, w*32+31]) ----
    // instr j (0,1): rows w*32 + j*16 + (lane>>2); global k-chunk XOR-swizzled.
    const int r_in = lane >> 2;                 // 0..15
    const int ch   = (lane & 3) ^ (r_in & 3);   // swizzled 16B k-chunk
    const unsigned short* aptr = Ag + (size_t)(wave * 32 + r_in) * K2_ + ch * 8;
    const unsigned short* bptr = Bg + (size_t)(wave * 32 + r_in) * K2_ + ch * 8;

    // ---- ds_read slot: logical chunk cq lives at physical slot cq ^ (row&3) ----
    const int cq   = lane >> 4;                       // logical 16B chunk 0..3
    const int slot = (cq ^ (l15 & 3)) << 3;           // shorts offset within 32-row

#define STAGE(bs, ks) do {                                         \
        unsigned short* _ad = &As[bs][wave * 1024];                \
        unsigned short* _bd = &Bs[bs][wave * 1024];                \
        gload_lds16(aptr + (ks),            _ad);                  \
        gload_lds16(aptr + 16 * K2_ + (ks), _ad + 512);            \
        gload_lds16(bptr + (ks),            _bd);                  \
        gload_lds16(bptr + 16 * K2_ + (ks), _bd + 512);            \
    } while (0)

#define COMPUTE(bs) do {                                                        \
        short8 af[4], bfr[4];                                                   \
        _Pragma("unroll")                                                       \
        for (int t = 0; t < 4; t++) {                                           \
            af[t]  = *(const short8*)&As[bs][(wm + t * 16 + l15) * 32 + slot];  \
            bfr[t] = *(const short8*)&Bs[bs][(wn + t * 16 + l15) * 32 + slot];  \
        }                                                                       \
        _Pragma("unroll")                                                       \
        for (int tm = 0; tm < 4; tm++)                                          \
            _Pragma("unroll")                                                   \
            for (int tn = 0; tn < 4; tn++)                                      \
                acc[tm][tn] = __builtin_amdgcn_mfma_f32_16x16x32_bf16(          \
                    af[tm], bfr[tn], acc[tm][tn], 0, 0, 0);                     \
    } while (0)

    // prologue: stage tile 0 into buffer 0
    STAGE(0, 0);
    int cur = 0;
    // main loop: tiles 0..62, prefetching tile t+1 while computing tile t
    for (int t = 0; t < 63; ++t) {
        STAGE(cur ^ 1, (t + 1) * 32);
        asm volatile("s_waitcnt vmcnt(4)" ::: "memory");  // tile t's 4 loads landed
        __builtin_amdgcn_s_barrier();
        COMPUTE(cur);
        asm volatile("s_waitcnt lgkmcnt(0)" ::: "memory"); // my ds_reads done
        __builtin_amdgcn_s_barrier();                      // buf[cur] safe to overwrite
        cur ^= 1;
    }
    // epilogue tile 63
    asm volatile("s_waitcnt vmcnt(0)" ::: "memory");
    __builtin_amdgcn_s_barrier();
    COMPUTE(cur);

#undef STAGE
#undef COMPUTE

    float rs[4][4];
    #pragma unroll
    for (int tm = 0; tm < 4; tm++)
        #pragma unroll
        for (int r = 0; r < 4; r++) rs[tm][r] = 0.f;

    #pragma unroll
    for (int tn = 0; tn < 4; tn++) {
        int ng = nt * 128 + wn + tn * 16 + l15;
        float vw = Vw[ng];
        float wv = wqbuf[b * H_ + ng];
        #pragma unroll
        for (int tm = 0; tm < 4; tm++)
            #pragma unroll
            for (int r = 0; r < 4; r++)
                rs[tm][r] += vw * fast_tanh(acc[tm][tn][r] + wv);
    }
    #pragma unroll
    for (int tm = 0; tm < 4; tm++)
        #pragma unroll
        for (int r = 0; r < 4; r++) {
            float v = rs[tm][r];
            v += __shfl_xor(v, 1, 64);
            v += __shfl_xor(v, 2, 64);
            v += __shfl_xor(v, 4, 64);
            v += __shfl_xor(v, 8, 64);
            rs[tm][r] = v;
        }
    if (l15 == 0) {
        int q = lane >> 4;
        #pragma unroll
        for (int tm = 0; tm < 4; tm++)
            #pragma unroll
            for (int r = 0; r < 4; r++)
                sc[wave >> 1][wm + tm * 16 + q * 4 + r] = rs[tm][r];
    }
    __syncthreads();
    if (tid < 128)
        partial[(size_t)(b * 8 + nt) * S_ + mt * 128 + tid] = sc[0][tid] + sc[1][tid];
}

// ---------------- fallback: round-1 inline-convert GEMM (if ws too small) ----------------
__global__ __launch_bounds__(256)
void gemm_scores_f32(const float* __restrict__ enc, const float* __restrict__ Uw,
                     const float* __restrict__ wqbuf, const float* __restrict__ Vw,
                     float* __restrict__ partial)
{
    const int b   = blockIdx.z;
    const int mt  = blockIdx.x;
    const int nt  = blockIdx.y;
    const int tid = threadIdx.x;
    const int wave = tid >> 6;
    const int lane = tid & 63;

    __shared__ unsigned short As[128][32];
    __shared__ unsigned short Bs[128][32];
    __shared__ float sc[2][128];

    const float* Ab = enc + ((size_t)b * S_ + (size_t)mt * 128) * K2_;
    const float* Bb = Uw + (size_t)nt * 128 * K2_;

    floatx4 acc[4][4];
    #pragma unroll
    for (int i = 0; i < 4; i++)
        #pragma unroll
        for (int j = 0; j < 4; j++)
            acc[i][j] = (floatx4){0.f, 0.f, 0.f, 0.f};

    const int wm  = (wave & 1) * 64;
    const int wn  = (wave >> 1) * 64;
    const int l15 = lane & 15;
    const int kq  = (lane >> 4) * 8;

    for (int ks = 0; ks < K2_; ks += 32) {
        #pragma unroll
        for (int i = 0; i < 4; i++) {
            int lin = tid + 256 * i;
            int row = lin >> 3;
            int kk  = (lin & 7) << 2;
            float4 av = *(const float4*)(Ab + (size_t)row * K2_ + ks + kk);
            float4 bv = *(const float4*)(Bb + (size_t)row * K2_ + ks + kk);
            ushort4 a4 = { f2bf(av.x), f2bf(av.y), f2bf(av.z), f2bf(av.w) };
            ushort4 b4 = { f2bf(bv.x), f2bf(bv.y), f2bf(bv.z), f2bf(bv.w) };
            *(ushort4*)&As[row][kk] = a4;
            *(ushort4*)&Bs[row][kk] = b4;
        }
        __syncthreads();

        short8 af[4], bfr[4];
        #pragma unroll
        for (int t = 0; t < 4; t++) {
            af[t]  = *(const short8*)&As[wm + t * 16 + l15][kq];
            bfr[t] = *(const short8*)&Bs[wn + t * 16 + l15][kq];
        }
        #pragma unroll
        for (int tm = 0; tm < 4; tm++)
            #pragma unroll
            for (int tn = 0; tn < 4; tn++)
                acc[tm][tn] = __builtin_amdgcn_mfma_f32_16x16x32_bf16(
                    af[tm], bfr[tn], acc[tm][tn], 0, 0, 0);
        __syncthreads();
    }

    float rs[4][4];
    #pragma unroll
    for (int tm = 0; tm < 4; tm++)
        #pragma unroll
        for (int r = 0; r < 4; r++) rs[tm][r] = 0.f;

    #pragma unroll
    for (int tn = 0; tn < 4; tn++) {
        int ng = nt * 128 + wn + tn * 16 + l15;
        float vw = Vw[ng];
        float wv = wqbuf[b * H_ + ng];
        #pragma unroll
        for (int tm = 0; tm < 4; tm++)
            #pragma unroll
            for (int r = 0; r < 4; r++)
                rs[tm][r] += vw * fast_tanh(acc[tm][tn][r] + wv);
    }
    #pragma unroll
    for (int tm = 0; tm < 4; tm++)
        #pragma unroll
        for (int r = 0; r < 4; r++) {
            float v = rs[tm][r];
            v += __shfl_xor(v, 1, 64);
            v += __shfl_xor(v, 2, 64);
            v += __shfl_xor(v, 4, 64);
            v += __shfl_xor(v, 8, 64);
            rs[tm][r] = v;
        }
    if (l15 == 0) {
        int q = lane >> 4;
        #pragma unroll
        for (int tm = 0; tm < 4; tm++)
            #pragma unroll
            for (int r = 0; r < 4; r++)
                sc[wave >> 1][wm + tm * 16 + q * 4 + r] = rs[tm][r];
    }
    __syncthreads();
    if (tid < 128)
        partial[(size_t)(b * 8 + nt) * S_ + mt * 128 + tid] = sc[0][tid] + sc[1][tid];
}

// ---------------- softmax over S per batch ----------------
__global__ __launch_bounds__(256)
void softmax_k(const float* __restrict__ partial, float* __restrict__ weights)
{
    const int b = blockIdx.x;
    const int tid = threadIdx.x;
    __shared__ float scores[S_];
    __shared__ float redm[4], reds[4];

    for (int s = tid; s < S_; s += 256) {
        float v = 0.f;
        #pragma unroll
        for (int nt = 0; nt < 8; nt++) v += partial[(size_t)(b * 8 + nt) * S_ + s];
        scores[s] = v;
    }
    __syncthreads();

    float m = -1e30f;
    for (int s = tid; s < S_; s += 256) m = fmaxf(m, scores[s]);
    #pragma unroll
    for (int off = 32; off > 0; off >>= 1) m = fmaxf(m, __shfl_xor(m, off, 64));
    if ((tid & 63) == 0) redm[tid >> 6] = m;
    __syncthreads();
    m = fmaxf(fmaxf(redm[0], redm[1]), fmaxf(redm[2], redm[3]));

    float sum = 0.f;
    for (int s = tid; s < S_; s += 256) {
        float e = __expf(scores[s] - m);
        scores[s] = e;
        sum += e;
    }
    #pragma unroll
    for (int off = 32; off > 0; off >>= 1) sum += __shfl_xor(sum, off, 64);
    if ((tid & 63) == 0) reds[tid >> 6] = sum;
    __syncthreads();
    sum = reds[0] + reds[1] + reds[2] + reds[3];
    float inv = 1.0f / sum;
    for (int s = tid; s < S_; s += 256) weights[b * S_ + s] = scores[s] * inv;
}

// ---------------- context: partial over 8 s-chunks, float4 columns ----------------
__global__ __launch_bounds__(256)
void context2_k(const float* __restrict__ enc, const float* __restrict__ weights,
                float* __restrict__ pctx)
{
    const int b = blockIdx.z, scnk = blockIdx.y, dblk = blockIdx.x;
    const int tid = threadIdx.x;
    __shared__ float w[256];
    w[tid] = weights[b * S_ + scnk * 256 + tid];
    __syncthreads();

    const float4* e = (const float4*)(enc + ((size_t)b * S_ + scnk * 256) * K2_)
                      + dblk * 256 + tid;
    float4 a0 = {0,0,0,0}, a1 = {0,0,0,0};
    #pragma unroll 4
    for (int s = 0; s < 256; s += 2) {
        float4 v0 = e[(size_t)s * 512];
        float4 v1 = e[(size_t)(s + 1) * 512];
        float w0 = w[s], w1 = w[s + 1];
        a0.x += w0 * v0.x; a0.y += w0 * v0.y; a0.z += w0 * v0.z; a0.w += w0 * v0.w;
        a1.x += w1 * v1.x; a1.y += w1 * v1.y; a1.z += w1 * v1.z; a1.w += w1 * v1.w;
    }
    float4 acc = { a0.x + a1.x, a0.y + a1.y, a0.z + a1.z, a0.w + a1.w };
    float4* o = (float4*)(pctx + (size_t)(b * 8 + scnk) * K2_) + dblk * 256 + tid;
    *o = acc;
}

__global__ __launch_bounds__(256)
void ctx_reduce_k(const float* __restrict__ pctx, float* __restrict__ out)
{
    const int i = blockIdx.x * 256 + threadIdx.x;   // 0..65535
    const int b = i >> 11, d = i & 2047;
    float s = 0.f;
    #pragma unroll
    for (int c = 0; c < 8; c++) s += pctx[(size_t)(b * 8 + c) * K2_ + d];
    out[i] = s;
}

extern "C" void kernel_launch(void* const* d_in, const int* in_sizes, int n_in,
                              void* d_out, int out_size, void* d_ws, size_t ws_size,
                              hipStream_t stream)
{
    const float* enc = (const float*)d_in[0];  // [32, 2048, 2048]
    const float* dh  = (const float*)d_in[1];  // [1, 32, 1024]
    const float* Ww  = (const float*)d_in[2];  // [1024, 1024]
    const float* Wb  = (const float*)d_in[3];  // [1024]
    const float* Uw  = (const float*)d_in[4];  // [1024, 2048]
    const float* Ub  = (const float*)d_in[5];  // [1024]
    const float* Vw  = (const float*)d_in[6];  // [1, 1024]
    // d_in[7] = V_b: unused (softmax shift-invariant)
    float* out = (float*)d_out;                // [32, 1, 2048] fp32

    float* wqbuf   = (float*)d_ws;                         // 32*1024
    float* partial = wqbuf + B_ * H_;                      // 32*8*2048
    float* weights = partial + B_ * 8 * S_;                // 32*2048
    float* pctx    = weights + B_ * S_;                    // 32*8*2048
    size_t small_bytes = (size_t)(B_*H_ + B_*8*S_ + B_*S_ + B_*8*S_) * 4;  // ~4.4 MB
    unsigned short* Uwb  = (unsigned short*)((char*)d_ws + small_bytes);    // 4 MB
    unsigned short* encb = Uwb + (size_t)H_ * K2_;                          // 256 MB
    size_t need = small_bytes + (size_t)H_ * K2_ * 2 + (size_t)B_ * S_ * K2_ * 2;

    wq_k<<<dim3(4, B_), dim3(256), 0, stream>>>(dh, Ww, Wb, Ub, wqbuf);

    if (ws_size >= need) {
        long long n8_enc = (long long)B_ * S_ * K2_ / 8;
        long long n8_uw  = (long long)H_ * K2_ / 8;
        cvt_bf16_k<<<dim3(8192), dim3(256), 0, stream>>>(enc, encb, n8_enc);
        cvt_bf16_k<<<dim3(1024), dim3(256), 0, stream>>>(Uw, Uwb, n8_uw);
        gemm_scores_bf16<<<dim3(16, 8, B_), dim3(256), 0, stream>>>(encb, Uwb, wqbuf, Vw, partial);
    } else {
        gemm_scores_f32<<<dim3(16, 8, B_), dim3(256), 0, stream>>>(enc, Uw, wqbuf, Vw, partial);
    }

    softmax_k<<<dim3(B_), dim3(256), 0, stream>>>(partial, weights);
    context2_k<<<dim3(2, 8, B_), dim3(256), 0, stream>>>(enc, weights, pctx);
    ctx_reduce_k<<<dim3(256), dim3(256), 0, stream>>>(pctx, out);
}